// Round 2
// baseline (290.621 us; speedup 1.0000x reference)
//
#include <hip/hip_runtime.h>
#include <hip/hip_bf16.h>

// Problem dims
#define S_  40000
#define G_  4000
#define B_  128
#define NI_ 4
#define E_  16
#define H1_ 1024
#define H2_ 256
#define EPSF 1e-5f
#define KSPLIT 10   // fc1 k-splits (4000 = 10 * 400, 400 = 25 * 16)

// ws layout (float indices)
#define OFF_TABS  ((size_t)0)                          // 8 floats: scale_tab[4], bias_tab[4]
#define OFF_STATS ((size_t)64)                         // 256 floats: sum[128], sqsum[128]
#define OFF_XST   ((size_t)1024)                       // xs_t [S][128]
#define OFF_GT    (OFF_XST + (size_t)S_ * B_)          // g_t  [G][128]
#define OFF_A1    (OFF_GT  + (size_t)G_ * B_)          // a1_t [G][128]
#define OFF_Y1P   (OFF_A1  + (size_t)G_ * B_)          // y1p  [KSPLIT][128][1024]
#define OFF_A2    (OFF_Y1P + (size_t)KSPLIT * B_ * H1_)// a2   [128][1024]

__device__ __forceinline__ float gelu_f(float x) {
    return 0.5f * x * (1.0f + erff(x * 0.70710678118654752f));
}

// K1: impact-attention tables (4 rows) + zero LN1 stats
__global__ void k1_prep(const float* __restrict__ emb, const float* __restrict__ proj_w,
                        const float* __restrict__ proj_b, const float* __restrict__ ln_i_w,
                        const float* __restrict__ ln_i_b, const float* __restrict__ scale_w,
                        const float* __restrict__ scale_b, const float* __restrict__ bias_w,
                        const float* __restrict__ bias_b, float* __restrict__ ws) {
    int tid = threadIdx.x;
    if (tid < 256) ws[OFF_STATS + tid] = 0.f;
    if (tid < NI_) {
        float h[E_];
        for (int e = 0; e < E_; ++e) {
            float s = proj_b[e];
            for (int f = 0; f < E_; ++f) s += emb[tid * E_ + f] * proj_w[e * E_ + f];
            h[e] = s;
        }
        float m = 0.f;
        for (int e = 0; e < E_; ++e) m += h[e];
        m *= (1.f / E_);
        float v = 0.f;
        for (int e = 0; e < E_; ++e) { float d = h[e] - m; v += d * d; }
        v *= (1.f / E_);
        float r = 1.f / sqrtf(v + EPSF);
        float sc = scale_b[0], bi = bias_b[0];
        for (int e = 0; e < E_; ++e) {
            float t = (h[e] - m) * r * ln_i_w[e] + ln_i_b[e];
            t = gelu_f(t);
            sc += t * scale_w[e];
            bi += t * bias_w[e];
        }
        ws[OFF_TABS + tid]     = sc;
        ws[OFF_TABS + 4 + tid] = bi;
    }
}

// K2: xs = x * 2*sigmoid(x*scale+bias), stored transposed xs_t[s][b]
__global__ __launch_bounds__(256) void k2_attn(const float* __restrict__ x,
                                               const int* __restrict__ ii,
                                               const float* __restrict__ tabs,
                                               float* __restrict__ xs_t) {
    __shared__ float tile[64][129];   // +1 pad: avoids 64-way bank conflict on write
    const int s0 = blockIdx.x * 64;
    const int ls = threadIdx.x & 63;
    const int bg = threadIdx.x >> 6;
    const int s  = s0 + ls;
    const int iv = ii[s];
    const float sc = tabs[iv];
    const float bi = tabs[4 + iv];
#pragma unroll
    for (int j = 0; j < 32; ++j) {
        int b = bg + j * 4;
        float xv = x[(size_t)b * S_ + s];                 // coalesced over ls
        float at = 2.f / (1.f + expf(-(xv * sc + bi)));
        tile[ls][b] = xv * at;
    }
    __syncthreads();
    const int b2 = threadIdx.x & 127;
    const int lg = threadIdx.x >> 7;
#pragma unroll
    for (int j = 0; j < 32; ++j) {
        int l = lg + j * 2;
        xs_t[(size_t)(s0 + l) * B_ + b2] = tile[l][b2];   // coalesced over b2
    }
}

// K3: stream mask rows (640 MB), ballot-detect hits, scatter xs_t rows into
// wave-private LDS gene accumulators. 8 gene rows/block, 2 rows/wave, no atomics.
__global__ __launch_bounds__(256) void k3_scan(const float* __restrict__ mask,
                                               const float* __restrict__ mw,
                                               const float* __restrict__ mb,
                                               const float* __restrict__ xs_t,
                                               float* __restrict__ g_t) {
    __shared__ float acc[8][128];
    const int lane = threadIdx.x & 63;
    const int wv   = threadIdx.x >> 6;
#pragma unroll
    for (int rr = 0; rr < 2; ++rr) {
        acc[wv * 2 + rr][lane]      = 0.f;
        acc[wv * 2 + rr][64 + lane] = 0.f;
    }
    const int rowbase = blockIdx.x * 8 + wv * 2;
    for (int rr = 0; rr < 2; ++rr) {
        const int row = rowbase + rr;
        const float4* __restrict__ mrow = (const float4*)(mask + (size_t)row * S_);
        const float*  __restrict__ mwrow = mw + (size_t)row * S_;
        float* accrow = &acc[wv * 2 + rr][0];
        // 10000 float4s per row: 40 iterations x 4 unrolled loads (last partial)
        for (int i = 0; i < 40; ++i) {
            const int base = i * 256;
            float4 vv[4];
#pragma unroll
            for (int u = 0; u < 4; ++u) {
                int idx = base + u * 64 + lane;
                vv[u] = (idx < 10000) ? mrow[idx] : make_float4(0.f, 0.f, 0.f, 0.f);
            }
#pragma unroll
            for (int u = 0; u < 4; ++u) {
                float4 v = vv[u];
                bool anyh = (v.x != 0.f) || (v.y != 0.f) || (v.z != 0.f) || (v.w != 0.f);
                unsigned long long wm = __ballot(anyh);
                if (wm) {
#pragma unroll
                    for (int c = 0; c < 4; ++c) {
                        float comp = (c == 0) ? v.x : (c == 1) ? v.y : (c == 2) ? v.z : v.w;
                        unsigned long long hm = __ballot(comp != 0.f);
                        while (hm) {
                            int l = __ffsll(hm) - 1;
                            hm &= hm - 1;
                            int s = (base + u * 64 + l) * 4 + c;
                            float mval = __shfl(comp, l);
                            float w = mval * mwrow[s];        // uniform addr -> broadcast
                            accrow[lane]      += w * xs_t[(size_t)s * B_ + lane];
                            accrow[64 + lane] += w * xs_t[(size_t)s * B_ + 64 + lane];
                        }
                    }
                }
            }
        }
    }
    // flush wave-private rows (no barrier needed)
#pragma unroll
    for (int rr = 0; rr < 2; ++rr) {
        int row = rowbase + rr;
        float bias = mb[row];
        g_t[(size_t)row * B_ + lane]      = acc[wv * 2 + rr][lane] + bias;
        g_t[(size_t)row * B_ + 64 + lane] = acc[wv * 2 + rr][64 + lane] + bias;
    }
}

// K4: per-b sum / sumsq over genes (for LN1)
__global__ __launch_bounds__(256) void k4_stats(const float* __restrict__ g_t,
                                                float* __restrict__ stats) {
    const int b = threadIdx.x & 127;
    const int h = threadIdx.x >> 7;
    const int g0 = blockIdx.x * 125;
    float s = 0.f, q = 0.f;
    for (int r = h; r < 125; r += 2) {
        float v = g_t[(size_t)(g0 + r) * B_ + b];
        s += v; q += v * v;
    }
    atomicAdd(&stats[b], s);
    atomicAdd(&stats[128 + b], q);
}

// K5: LN1 + gelu -> a1_t[g][b]
__global__ __launch_bounds__(256) void k5_ln1(const float* __restrict__ g_t,
                                              const float* __restrict__ stats,
                                              const float* __restrict__ ln1_w,
                                              const float* __restrict__ ln1_b,
                                              float* __restrict__ a1_t) {
    const int idx = blockIdx.x * 256 + threadIdx.x;
    const int b = idx & 127;
    const int g = idx >> 7;
    const float m   = stats[b] * (1.f / G_);
    const float var = stats[128 + b] * (1.f / G_) - m * m;
    const float r   = 1.f / sqrtf(var + EPSF);
    const float val = (g_t[idx] - m) * r * ln1_w[g] + ln1_b[g];
    a1_t[idx] = gelu_f(val);
}

// K6: fc1 GEMM, fp32, k-split partials. Block = 128b x 64h, K-chunk 16.
__global__ __launch_bounds__(256) void k6_fc1(const float* __restrict__ a1_t,
                                              const float* __restrict__ fc1_w,
                                              float* __restrict__ y1p) {
    __shared__ float As[16 * 128];
    __shared__ float Ws[16][64];
    const int tid  = threadIdx.x;
    const int lane = tid & 63;
    const int wv   = tid >> 6;
    const int h0   = blockIdx.x * 64;
    const int k0   = blockIdx.y * 400;
    const int hh   = wv * 16;
    float acc0[16], acc1[16];
#pragma unroll
    for (int j = 0; j < 16; ++j) { acc0[j] = 0.f; acc1[j] = 0.f; }
    for (int ch = 0; ch < 25; ++ch) {
        const int kc = k0 + ch * 16;
        __syncthreads();
        { // stage A tile [16k][128b] (contiguous 8 KB of a1_t)
            const float4* src = (const float4*)(a1_t + (size_t)kc * B_);
            float4* dst = (float4*)As;
            dst[tid]       = src[tid];
            dst[tid + 256] = src[tid + 256];
        }
        { // stage W tile transposed -> Ws[k][h]
            const int h = tid & 63, q = tid >> 6;
            float4 w4 = *(const float4*)(fc1_w + (size_t)(h0 + h) * G_ + kc + q * 4);
            Ws[q * 4 + 0][h] = w4.x; Ws[q * 4 + 1][h] = w4.y;
            Ws[q * 4 + 2][h] = w4.z; Ws[q * 4 + 3][h] = w4.w;
        }
        __syncthreads();
#pragma unroll
        for (int k = 0; k < 16; ++k) {
            const float a0  = As[k * 128 + lane];
            const float a1v = As[k * 128 + 64 + lane];
            const float4* wrow = (const float4*)(&Ws[k][hh]);
#pragma unroll
            for (int jq = 0; jq < 4; ++jq) {
                float4 w4 = wrow[jq];
                acc0[jq * 4 + 0] += a0 * w4.x;  acc1[jq * 4 + 0] += a1v * w4.x;
                acc0[jq * 4 + 1] += a0 * w4.y;  acc1[jq * 4 + 1] += a1v * w4.y;
                acc0[jq * 4 + 2] += a0 * w4.z;  acc1[jq * 4 + 2] += a1v * w4.z;
                acc0[jq * 4 + 3] += a0 * w4.w;  acc1[jq * 4 + 3] += a1v * w4.w;
            }
        }
    }
    float* out0 = y1p + ((size_t)blockIdx.y * B_ + lane) * H1_ + h0 + hh;
    float* out1 = out0 + (size_t)64 * H1_;
    float4* o0 = (float4*)out0;
    float4* o1 = (float4*)out1;
#pragma unroll
    for (int q = 0; q < 4; ++q) {
        o0[q] = make_float4(acc0[q*4+0], acc0[q*4+1], acc0[q*4+2], acc0[q*4+3]);
        o1[q] = make_float4(acc1[q*4+0], acc1[q*4+1], acc1[q*4+2], acc1[q*4+3]);
    }
}

// K7: reduce k-split partials + fc1 bias, LN_A + gelu -> a2[b][h]
__global__ __launch_bounds__(256) void k7_lnA(const float* __restrict__ y1p,
                                              const float* __restrict__ fc1_b,
                                              const float* __restrict__ lnA_w,
                                              const float* __restrict__ lnA_b,
                                              float* __restrict__ a2) {
    const int b = blockIdx.x, tid = threadIdx.x, lane = tid & 63, wv = tid >> 6;
    __shared__ float red[8];
    float v[4];
    float s_ = 0.f, q_ = 0.f;
#pragma unroll
    for (int j = 0; j < 4; ++j) {
        int h = tid + j * 256;
        float s = fc1_b[h];
        for (int ks = 0; ks < KSPLIT; ++ks)
            s += y1p[(size_t)ks * B_ * H1_ + (size_t)b * H1_ + h];
        v[j] = s; s_ += s; q_ += s * s;
    }
    for (int off = 32; off; off >>= 1) { s_ += __shfl_down(s_, off); q_ += __shfl_down(q_, off); }
    if (lane == 0) { red[wv] = s_; red[4 + wv] = q_; }
    __syncthreads();
    float Ssum = red[0] + red[1] + red[2] + red[3];
    float Qsum = red[4] + red[5] + red[6] + red[7];
    float m = Ssum / 1024.f, var = Qsum / 1024.f - m * m;
    float r = 1.f / sqrtf(var + EPSF);
#pragma unroll
    for (int j = 0; j < 4; ++j) {
        int h = tid + j * 256;
        float val = (v[j] - m) * r * lnA_w[h] + lnA_b[h];
        a2[(size_t)b * H1_ + h] = gelu_f(val);
    }
}

// K8: fc2 + LN_B + gelu + out-dot, one block per batch row, fp32 output
__global__ __launch_bounds__(256) void k8_head(const float* __restrict__ a2,
                                               const float* __restrict__ fc2_w,
                                               const float* __restrict__ fc2_b,
                                               const float* __restrict__ lnB_w,
                                               const float* __restrict__ lnB_b,
                                               const float* __restrict__ out_w,
                                               const float* __restrict__ out_b,
                                               float* __restrict__ out) {
    const int b = blockIdx.x, tid = threadIdx.x, lane = tid & 63, wv = tid >> 6;
    __shared__ float a_s[H1_];
    __shared__ float y_s[H2_];
    __shared__ float red[8];
    { // stage a2 row
        const float4* src = (const float4*)(a2 + (size_t)b * H1_);
        ((float4*)a_s)[tid] = src[tid];   // 256 float4 = 1024 floats
    }
    __syncthreads();
    // each wave computes 64 outputs via 64-lane dot + shuffle reduce
    for (int oi = 0; oi < 64; ++oi) {
        int o = wv * 64 + oi;
        const float4* wr = (const float4*)(fc2_w + (size_t)o * H1_);
        float d = 0.f;
#pragma unroll
        for (int q = 0; q < 4; ++q) {
            float4 ww = wr[lane + 64 * q];
            float4 aa = ((const float4*)a_s)[lane + 64 * q];
            d += aa.x * ww.x + aa.y * ww.y + aa.z * ww.z + aa.w * ww.w;
        }
        for (int off = 32; off; off >>= 1) d += __shfl_down(d, off);
        if (lane == 0) y_s[o] = d + fc2_b[o];
    }
    __syncthreads();
    float yv = y_s[tid];
    float s_ = yv, q_ = yv * yv;
    for (int off = 32; off; off >>= 1) { s_ += __shfl_down(s_, off); q_ += __shfl_down(q_, off); }
    if (lane == 0) { red[wv] = s_; red[4 + wv] = q_; }
    __syncthreads();
    float Ssum = red[0] + red[1] + red[2] + red[3];
    float Qsum = red[4] + red[5] + red[6] + red[7];
    float m = Ssum / (float)H2_, var = Qsum / (float)H2_ - m * m;
    float r = 1.f / sqrtf(var + EPSF);
    float val = gelu_f((yv - m) * r * lnB_w[tid] + lnB_b[tid]) * out_w[tid];
    __syncthreads();   // before reusing red[]
    float t_ = val;
    for (int off = 32; off; off >>= 1) t_ += __shfl_down(t_, off);
    if (lane == 0) red[wv] = t_;
    __syncthreads();
    if (tid == 0)
        out[b] = red[0] + red[1] + red[2] + red[3] + out_b[0];
}

extern "C" void kernel_launch(void* const* d_in, const int* in_sizes, int n_in,
                              void* d_out, int out_size, void* d_ws, size_t ws_size,
                              hipStream_t stream) {
    const float* x       = (const float*)d_in[0];
    const int*   ii      = (const int*)  d_in[1];
    const float* mask    = (const float*)d_in[2];
    const float* emb     = (const float*)d_in[3];
    const float* proj_w  = (const float*)d_in[4];
    const float* proj_b  = (const float*)d_in[5];
    const float* ln_i_w  = (const float*)d_in[6];
    const float* ln_i_b  = (const float*)d_in[7];
    const float* scale_w = (const float*)d_in[8];
    const float* scale_b = (const float*)d_in[9];
    const float* bias_w  = (const float*)d_in[10];
    const float* bias_b  = (const float*)d_in[11];
    const float* mw      = (const float*)d_in[12];
    const float* mb      = (const float*)d_in[13];
    const float* ln1_w   = (const float*)d_in[14];
    const float* ln1_b   = (const float*)d_in[15];
    const float* fc1_w   = (const float*)d_in[16];
    const float* fc1_b   = (const float*)d_in[17];
    const float* lnA_w   = (const float*)d_in[18];
    const float* lnA_b   = (const float*)d_in[19];
    const float* fc2_w   = (const float*)d_in[20];
    const float* fc2_b   = (const float*)d_in[21];
    const float* lnB_w   = (const float*)d_in[22];
    const float* lnB_b   = (const float*)d_in[23];
    const float* out_w   = (const float*)d_in[24];
    const float* out_b   = (const float*)d_in[25];

    float* ws    = (float*)d_ws;
    float* tabs  = ws + OFF_TABS;
    float* stats = ws + OFF_STATS;
    float* xs_t  = ws + OFF_XST;
    float* g_t   = ws + OFF_GT;
    float* a1_t  = ws + OFF_A1;
    float* y1p   = ws + OFF_Y1P;
    float* a2    = ws + OFF_A2;
    float* out   = (float*)d_out;

    hipLaunchKernelGGL(k1_prep, dim3(1), dim3(256), 0, stream,
                       emb, proj_w, proj_b, ln_i_w, ln_i_b, scale_w, scale_b, bias_w, bias_b, ws);
    hipLaunchKernelGGL(k2_attn, dim3(S_ / 64), dim3(256), 0, stream, x, ii, tabs, xs_t);
    hipLaunchKernelGGL(k3_scan, dim3(G_ / 8), dim3(256), 0, stream, mask, mw, mb, xs_t, g_t);
    hipLaunchKernelGGL(k4_stats, dim3(32), dim3(256), 0, stream, g_t, stats);
    hipLaunchKernelGGL(k5_ln1, dim3(G_ * B_ / 256), dim3(256), 0, stream, g_t, stats, ln1_w, ln1_b, a1_t);
    hipLaunchKernelGGL(k6_fc1, dim3(H1_ / 64, KSPLIT), dim3(256), 0, stream, a1_t, fc1_w, y1p);
    hipLaunchKernelGGL(k7_lnA, dim3(B_), dim3(256), 0, stream, y1p, fc1_b, lnA_w, lnA_b, a2);
    hipLaunchKernelGGL(k8_head, dim3(B_), dim3(256), 0, stream,
                       a2, fc2_w, fc2_b, lnB_w, lnB_b, out_w, out_b, out);
}